// Round 3
// baseline (983.227 us; speedup 1.0000x reference)
//
#include <hip/hip_runtime.h>
#include <math.h>

#define B 2048
#define C 1024
#define NBLK 256

typedef _Float16 v2h __attribute__((ext_vector_type(2)));

// ---------------------------------------------------------------------------
// Kernel 1: row softmax of y/2 for both inputs -> fp16 output.
// grid 2*B blocks, 256 threads; each thread owns 4 elements of the row.
// ---------------------------------------------------------------------------
__global__ __launch_bounds__(256) void softmax_k(const float* __restrict__ ys,
                                                 const float* __restrict__ yt,
                                                 _Float16* __restrict__ ps,
                                                 _Float16* __restrict__ pt) {
    int b = blockIdx.x;
    const float* in;
    _Float16* out;
    if (b < B) { in = ys + (size_t)b * C;        out = ps + (size_t)b * C; }
    else       { in = yt + (size_t)(b - B) * C;  out = pt + (size_t)(b - B) * C; }
    int tid = threadIdx.x;
    int lane = tid & 63, wave = tid >> 6;

    float4 v = reinterpret_cast<const float4*>(in)[tid];
    v.x *= 0.5f; v.y *= 0.5f; v.z *= 0.5f; v.w *= 0.5f;

    float mx = fmaxf(fmaxf(v.x, v.y), fmaxf(v.z, v.w));
    #pragma unroll
    for (int m = 32; m >= 1; m >>= 1) mx = fmaxf(mx, __shfl_xor(mx, m, 64));
    __shared__ float redm[4];
    if (lane == 0) redm[wave] = mx;
    __syncthreads();
    mx = fmaxf(fmaxf(redm[0], redm[1]), fmaxf(redm[2], redm[3]));

    float4 e;
    e.x = expf(v.x - mx); e.y = expf(v.y - mx);
    e.z = expf(v.z - mx); e.w = expf(v.w - mx);
    float s = e.x + e.y + e.z + e.w;
    #pragma unroll
    for (int m = 32; m >= 1; m >>= 1) s += __shfl_xor(s, m, 64);
    __shared__ float reds[4];
    if (lane == 0) reds[wave] = s;
    __syncthreads();
    s = reds[0] + reds[1] + reds[2] + reds[3];

    float inv = 1.0f / s;
    float2 st;
    v2h* sp = (v2h*)&st;
    sp[0] = (v2h){(_Float16)(e.x * inv), (_Float16)(e.y * inv)};
    sp[1] = (v2h){(_Float16)(e.z * inv), (_Float16)(e.w * inv)};
    reinterpret_cast<float2*>(out)[tid] = st;
}

// ---------------------------------------------------------------------------
// Kernel 2: K[i][j] = exp(20*S - 20), S = sum_c min(ps[i,c], pt[j,c])  (fp16)
// 128x128 tile, 256 threads, 8x8 frags split as rows {ty*4..+3} U {64+ty*4..+3}
// (keeps every LDS b128 read at <=2-way bank aliasing). BK=32 halfs.
// Inner: v_pk_min_f16 + v_dot2_f32_f16 = 1 VALU instr per element.
// ---------------------------------------------------------------------------
__global__ __launch_bounds__(256) void cdist_k(const _Float16* __restrict__ ps,
                                               const _Float16* __restrict__ pt,
                                               float* __restrict__ Km) {
    __shared__ __align__(16) v2h As[16][132];   // [k2][row], pad 132
    __shared__ __align__(16) v2h Bs[16][132];
    int tid = threadIdx.x;
    int tx = tid & 15, ty = tid >> 4;
    int r0 = blockIdx.y * 128, c0 = blockIdx.x * 128;

    float acc[8][8];
    #pragma unroll
    for (int i = 0; i < 8; ++i)
        #pragma unroll
        for (int j = 0; j < 8; ++j) acc[i][j] = 0.f;

    int lr = tid >> 1;          // staging row 0..127
    int lq = tid & 1;           // which 16-half group
    const float4* pa = reinterpret_cast<const float4*>(ps + (size_t)(r0 + lr) * C);
    const float4* pb = reinterpret_cast<const float4*>(pt + (size_t)(c0 + lr) * C);
    const v2h one2 = {(_Float16)1.0f, (_Float16)1.0f};

    for (int ch = 0; ch < 32; ++ch) {           // 32 chunks of 32 halfs
        float4 a0 = pa[ch * 4 + lq * 2];
        float4 a1 = pa[ch * 4 + lq * 2 + 1];
        float4 b0 = pb[ch * 4 + lq * 2];
        float4 b1 = pb[ch * 4 + lq * 2 + 1];
        v2h* ah0 = (v2h*)&a0; v2h* ah1 = (v2h*)&a1;
        v2h* bh0 = (v2h*)&b0; v2h* bh1 = (v2h*)&b1;
        #pragma unroll
        for (int c2 = 0; c2 < 4; ++c2) {
            As[lq * 8 + c2][lr]     = ah0[c2];
            As[lq * 8 + 4 + c2][lr] = ah1[c2];
            Bs[lq * 8 + c2][lr]     = bh0[c2];
            Bs[lq * 8 + 4 + c2][lr] = bh1[c2];
        }
        __syncthreads();
        #pragma unroll
        for (int k2 = 0; k2 < 16; ++k2) {
            v2h a2[8], b2[8];
            *(float4*)&a2[0] = *(const float4*)&As[k2][ty * 4];
            *(float4*)&a2[4] = *(const float4*)&As[k2][64 + ty * 4];
            *(float4*)&b2[0] = *(const float4*)&Bs[k2][tx * 4];
            *(float4*)&b2[4] = *(const float4*)&Bs[k2][64 + tx * 4];
            #pragma unroll
            for (int i = 0; i < 8; ++i)
                #pragma unroll
                for (int j = 0; j < 8; ++j) {
                    v2h m = __builtin_elementwise_min(a2[i], b2[j]);
#if __has_builtin(__builtin_amdgcn_fdot2)
                    acc[i][j] = __builtin_amdgcn_fdot2(m, one2, acc[i][j], false);
#else
                    acc[i][j] += (float)m.x + (float)m.y;
#endif
                }
        }
        __syncthreads();
    }

    #pragma unroll
    for (int i = 0; i < 8; ++i) {
        int row = r0 + ((i < 4) ? (ty * 4 + i) : (64 + ty * 4 + (i - 4)));
        float4 k0, k1;
        k0.x = __expf(20.f * acc[i][0] - 20.f);
        k0.y = __expf(20.f * acc[i][1] - 20.f);
        k0.z = __expf(20.f * acc[i][2] - 20.f);
        k0.w = __expf(20.f * acc[i][3] - 20.f);
        k1.x = __expf(20.f * acc[i][4] - 20.f);
        k1.y = __expf(20.f * acc[i][5] - 20.f);
        k1.z = __expf(20.f * acc[i][6] - 20.f);
        k1.w = __expf(20.f * acc[i][7] - 20.f);
        *reinterpret_cast<float4*>(&Km[(size_t)row * B + c0 + tx * 4]) = k0;
        *reinterpret_cast<float4*>(&Km[(size_t)row * B + c0 + 64 + tx * 4]) = k1;
    }
}

// ---------------------------------------------------------------------------
// Kernel 3: init svec[0]=1, svec[1..20]=0, bar=0, out=0. grid 160x256.
// ---------------------------------------------------------------------------
__global__ __launch_bounds__(256) void init_k(float* __restrict__ svec,
                                              float* __restrict__ out,
                                              int* __restrict__ bar) {
    int i = blockIdx.x * 256 + threadIdx.x;
    if (i < B) svec[i] = 1.0f;
    svec[B + i] = 0.f;              // i covers 0..20*B-1
    if (i < 32) bar[i] = 0;
    if (i == 0) out[0] = 0.f;
}

// ---------------------------------------------------------------------------
// Persistent Sinkhorn + loss. 256 blocks (1/CU, co-resident), 256 threads.
// Each block owns 8 rows of K in LDS. Grid barrier per iteration.
// ---------------------------------------------------------------------------
__device__ __forceinline__ void gbar(int* ctr) {
    __syncthreads();
    if (threadIdx.x == 0) {
        __hip_atomic_fetch_add(ctr, 1, __ATOMIC_ACQ_REL, __HIP_MEMORY_SCOPE_AGENT);
        while (__hip_atomic_load(ctr, __ATOMIC_RELAXED, __HIP_MEMORY_SCOPE_AGENT) < NBLK)
            __builtin_amdgcn_s_sleep(2);
    }
    __threadfence();
    __syncthreads();
}

__global__ __launch_bounds__(256, 1) void sinkhorn_k(const float* __restrict__ Km,
                                                     float* __restrict__ svec,
                                                     float* __restrict__ out,
                                                     int* __restrict__ bar) {
    __shared__ float Krow[8][B];    // 64 KB: this block's 8 rows of K
    __shared__ float binv[B];       // 8 KB
    __shared__ float a_lds[8];
    int tid = threadIdx.x;
    int lane = tid & 63, wave = tid >> 6;
    int bid = blockIdx.x;

    // load 8 rows (64 KB) into LDS, coalesced float4
    const float4* src = reinterpret_cast<const float4*>(Km + (size_t)bid * 8 * B);
    float4* dst = reinterpret_cast<float4*>(&Krow[0][0]);
    #pragma unroll
    for (int t = 0; t < 16; ++t) dst[t * 256 + tid] = src[t * 256 + tid];

    for (int it = 1; it <= 20; ++it) {
        float* sprev = svec + (size_t)(it - 1) * B;
        for (int j = tid; j < B; j += 256)
            binv[j] = 1.0f / __hip_atomic_load(&sprev[j], __ATOMIC_RELAXED,
                                               __HIP_MEMORY_SCOPE_AGENT);
        __syncthreads();

        // row pass: a_i = 1 / sum_j Krow[i][j]*binv[j]; wave handles 2 rows
        #pragma unroll
        for (int rr = 0; rr < 2; ++rr) {
            int row = wave * 2 + rr;
            const float2* kr = reinterpret_cast<const float2*>(&Krow[row][0]);
            const float2* bv = reinterpret_cast<const float2*>(&binv[0]);
            float acc = 0.f;
            #pragma unroll
            for (int t = 0; t < 16; ++t) {
                float2 k2 = kr[t * 64 + lane];
                float2 b2 = bv[t * 64 + lane];
                acc += k2.x * b2.x + k2.y * b2.y;
            }
            #pragma unroll
            for (int m = 32; m >= 1; m >>= 1) acc += __shfl_xor(acc, m, 64);
            if (lane == 0) a_lds[row] = 1.0f / acc;
        }
        __syncthreads();

        // col pass: partial col sums -> atomicAdd into svec[it]
        float* sout = svec + (size_t)it * B;
        #pragma unroll
        for (int t = 0; t < 8; ++t) {
            int j = t * 256 + tid;
            float s = 0.f;
            #pragma unroll
            for (int i = 0; i < 8; ++i) s += Krow[i][j] * a_lds[i];
            atomicAdd(&sout[j], s);
        }
        gbar(&bar[it - 1]);
    }

    // loss: sum_ij a_i K_ij b_j * (-0.1 ln K_ij), b = 1/svec[20]
    for (int j = tid; j < B; j += 256)
        binv[j] = 1.0f / __hip_atomic_load(&svec[(size_t)20 * B + j],
                                           __ATOMIC_RELAXED, __HIP_MEMORY_SCOPE_AGENT);
    __syncthreads();
    float wsum = 0.f;
    #pragma unroll
    for (int rr = 0; rr < 2; ++rr) {
        int row = wave * 2 + rr;
        const float2* kr = reinterpret_cast<const float2*>(&Krow[row][0]);
        const float2* bv = reinterpret_cast<const float2*>(&binv[0]);
        float acc = 0.f;
        for (int t = 0; t < 16; ++t) {
            float2 k2 = kr[t * 64 + lane];
            float2 b2 = bv[t * 64 + lane];
            acc += k2.x * b2.x * __logf(k2.x);
            acc += k2.y * b2.y * __logf(k2.y);
        }
        #pragma unroll
        for (int m = 32; m >= 1; m >>= 1) acc += __shfl_xor(acc, m, 64);
        wsum += -0.1f * a_lds[row] * acc;
    }
    if (lane == 0) atomicAdd(out, 0.001f * wsum);
}

// ---------------------------------------------------------------------------
extern "C" void kernel_launch(void* const* d_in, const int* in_sizes, int n_in,
                              void* d_out, int out_size, void* d_ws, size_t ws_size,
                              hipStream_t stream) {
    const float* ys = (const float*)d_in[0];
    const float* yt = (const float*)d_in[1];
    float* out = (float*)d_out;

    char* wsb = (char*)d_ws;
    _Float16* ps = (_Float16*)wsb;                               // 4 MB
    _Float16* pt = (_Float16*)(wsb + (size_t)B * C * 2);         // 4 MB
    float* Km    = (float*)(wsb + (size_t)2 * B * C * 2);        // 16.8 MB
    float* svec  = Km + (size_t)B * B;                           // 21*B floats
    int*   bar   = (int*)(svec + (size_t)21 * B);                // 32 ints

    init_k<<<160, 256, 0, stream>>>(svec, out, bar);
    softmax_k<<<2 * B, 256, 0, stream>>>(ys, yt, ps, pt);
    cdist_k<<<dim3(16, 16), 256, 0, stream>>>(ps, pt, Km);
    sinkhorn_k<<<NBLK, 256, 0, stream>>>(Km, svec, out, bar);
}

// Round 4
// 569.351 us; speedup vs baseline: 1.7269x; 1.7269x over previous
//
#include <hip/hip_runtime.h>
#include <math.h>

#define B 2048
#define C 1024

typedef _Float16 v2h __attribute__((ext_vector_type(2)));

// ---------------------------------------------------------------------------
// Kernel 1: row softmax of y/2 for both inputs -> fp16 output.
// ---------------------------------------------------------------------------
__global__ __launch_bounds__(256) void softmax_k(const float* __restrict__ ys,
                                                 const float* __restrict__ yt,
                                                 _Float16* __restrict__ ps,
                                                 _Float16* __restrict__ pt) {
    int b = blockIdx.x;
    const float* in;
    _Float16* out;
    if (b < B) { in = ys + (size_t)b * C;        out = ps + (size_t)b * C; }
    else       { in = yt + (size_t)(b - B) * C;  out = pt + (size_t)(b - B) * C; }
    int tid = threadIdx.x;
    int lane = tid & 63, wave = tid >> 6;

    float4 v = reinterpret_cast<const float4*>(in)[tid];
    v.x *= 0.5f; v.y *= 0.5f; v.z *= 0.5f; v.w *= 0.5f;

    float mx = fmaxf(fmaxf(v.x, v.y), fmaxf(v.z, v.w));
    #pragma unroll
    for (int m = 32; m >= 1; m >>= 1) mx = fmaxf(mx, __shfl_xor(mx, m, 64));
    __shared__ float redm[4];
    if (lane == 0) redm[wave] = mx;
    __syncthreads();
    mx = fmaxf(fmaxf(redm[0], redm[1]), fmaxf(redm[2], redm[3]));

    float4 e;
    e.x = expf(v.x - mx); e.y = expf(v.y - mx);
    e.z = expf(v.z - mx); e.w = expf(v.w - mx);
    float s = e.x + e.y + e.z + e.w;
    #pragma unroll
    for (int m = 32; m >= 1; m >>= 1) s += __shfl_xor(s, m, 64);
    __shared__ float reds[4];
    if (lane == 0) reds[wave] = s;
    __syncthreads();
    s = reds[0] + reds[1] + reds[2] + reds[3];

    float inv = 1.0f / s;
    float2 st;
    v2h* sp = (v2h*)&st;
    sp[0] = (v2h){(_Float16)(e.x * inv), (_Float16)(e.y * inv)};
    sp[1] = (v2h){(_Float16)(e.z * inv), (_Float16)(e.w * inv)};
    reinterpret_cast<float2*>(out)[tid] = st;
}

// ---------------------------------------------------------------------------
// Kernel 2: K[i][j] = exp(20*S - 20), S = sum_c min(ps[i,c], pt[j,c])  (fp16)
// 128x128 tile, 256 threads, 8x8 frags split +-64. pk_min + dot2 inner loop.
// ---------------------------------------------------------------------------
__global__ __launch_bounds__(256) void cdist_k(const _Float16* __restrict__ ps,
                                               const _Float16* __restrict__ pt,
                                               float* __restrict__ Km) {
    __shared__ __align__(16) v2h As[16][132];
    __shared__ __align__(16) v2h Bs[16][132];
    int tid = threadIdx.x;
    int tx = tid & 15, ty = tid >> 4;
    int r0 = blockIdx.y * 128, c0 = blockIdx.x * 128;

    float acc[8][8];
    #pragma unroll
    for (int i = 0; i < 8; ++i)
        #pragma unroll
        for (int j = 0; j < 8; ++j) acc[i][j] = 0.f;

    int lr = tid >> 1;
    int lq = tid & 1;
    const float4* pa = reinterpret_cast<const float4*>(ps + (size_t)(r0 + lr) * C);
    const float4* pb = reinterpret_cast<const float4*>(pt + (size_t)(c0 + lr) * C);
    const v2h one2 = {(_Float16)1.0f, (_Float16)1.0f};

    for (int ch = 0; ch < 32; ++ch) {
        float4 a0 = pa[ch * 4 + lq * 2];
        float4 a1 = pa[ch * 4 + lq * 2 + 1];
        float4 b0 = pb[ch * 4 + lq * 2];
        float4 b1 = pb[ch * 4 + lq * 2 + 1];
        v2h* ah0 = (v2h*)&a0; v2h* ah1 = (v2h*)&a1;
        v2h* bh0 = (v2h*)&b0; v2h* bh1 = (v2h*)&b1;
        #pragma unroll
        for (int c2 = 0; c2 < 4; ++c2) {
            As[lq * 8 + c2][lr]     = ah0[c2];
            As[lq * 8 + 4 + c2][lr] = ah1[c2];
            Bs[lq * 8 + c2][lr]     = bh0[c2];
            Bs[lq * 8 + 4 + c2][lr] = bh1[c2];
        }
        __syncthreads();
        #pragma unroll
        for (int k2 = 0; k2 < 16; ++k2) {
            v2h a2[8], b2[8];
            *(float4*)&a2[0] = *(const float4*)&As[k2][ty * 4];
            *(float4*)&a2[4] = *(const float4*)&As[k2][64 + ty * 4];
            *(float4*)&b2[0] = *(const float4*)&Bs[k2][tx * 4];
            *(float4*)&b2[4] = *(const float4*)&Bs[k2][64 + tx * 4];
            #pragma unroll
            for (int i = 0; i < 8; ++i)
                #pragma unroll
                for (int j = 0; j < 8; ++j) {
                    v2h m = __builtin_elementwise_min(a2[i], b2[j]);
#if __has_builtin(__builtin_amdgcn_fdot2)
                    acc[i][j] = __builtin_amdgcn_fdot2(m, one2, acc[i][j], false);
#else
                    acc[i][j] += (float)m.x + (float)m.y;
#endif
                }
        }
        __syncthreads();
    }

    #pragma unroll
    for (int i = 0; i < 8; ++i) {
        int row = r0 + ((i < 4) ? (ty * 4 + i) : (64 + ty * 4 + (i - 4)));
        float4 k0, k1;
        k0.x = __expf(20.f * acc[i][0] - 20.f);
        k0.y = __expf(20.f * acc[i][1] - 20.f);
        k0.z = __expf(20.f * acc[i][2] - 20.f);
        k0.w = __expf(20.f * acc[i][3] - 20.f);
        k1.x = __expf(20.f * acc[i][4] - 20.f);
        k1.y = __expf(20.f * acc[i][5] - 20.f);
        k1.z = __expf(20.f * acc[i][6] - 20.f);
        k1.w = __expf(20.f * acc[i][7] - 20.f);
        *reinterpret_cast<float4*>(&Km[(size_t)row * B + c0 + tx * 4]) = k0;
        *reinterpret_cast<float4*>(&Km[(size_t)row * B + c0 + 64 + tx * 4]) = k1;
    }
}

// ---------------------------------------------------------------------------
// Kernel 3: svec[0][j] = 1.0
// ---------------------------------------------------------------------------
__global__ void init1_k(float* __restrict__ s0) {
    int i = blockIdx.x * 256 + threadIdx.x;
    if (i < B) s0[i] = 1.0f;
}

// ---------------------------------------------------------------------------
// Kernel 4: one Sinkhorn iteration. 128 blocks x 1024 threads; block owns 16
// rows; thread owns 2 columns (rotated by 16*bid to spread atomic traffic).
// K values stay in registers across both phases. a_i = 1/(K.binv) via
// shfl+LDS reduce; col partials -> 2 rotated atomicAdds per thread.
// ---------------------------------------------------------------------------
__global__ __launch_bounds__(1024) void iter_k(const float* __restrict__ Km,
                                               const float* __restrict__ sprev,
                                               float* __restrict__ snext,
                                               float* __restrict__ a_glob) {
    __shared__ float part[16][16];
    __shared__ float a_lds[16];
    int t = threadIdx.x;
    int lane = t & 63, wv = t >> 6;
    int bid = blockIdx.x;
    int r0 = bid * 16;
    int jx = (2 * t + 16 * bid) & (B - 1);   // even, 8B-aligned

    float2 sv = *reinterpret_cast<const float2*>(&sprev[jx]);
    float bx = 1.0f / sv.x, by = 1.0f / sv.y;

    float2 kreg[16];
    float accr[16];
    #pragma unroll
    for (int i = 0; i < 16; ++i) {
        float2 k2 = *reinterpret_cast<const float2*>(&Km[(size_t)(r0 + i) * B + jx]);
        kreg[i] = k2;
        accr[i] = k2.x * bx + k2.y * by;
    }
    #pragma unroll
    for (int i = 0; i < 16; ++i) {
        float v = accr[i];
        #pragma unroll
        for (int m = 32; m >= 1; m >>= 1) v += __shfl_xor(v, m, 64);
        if (lane == 0) part[i][wv] = v;
    }
    __syncthreads();
    if (t < 16) {
        float s = 0.f;
        #pragma unroll
        for (int w = 0; w < 16; ++w) s += part[t][w];
        float av = 1.0f / s;
        a_lds[t] = av;
        a_glob[r0 + t] = av;
    }
    __syncthreads();

    float cx = 0.f, cy = 0.f;
    #pragma unroll
    for (int i = 0; i < 16; ++i) {
        float ai = a_lds[i];
        cx += ai * kreg[i].x;
        cy += ai * kreg[i].y;
    }
    atomicAdd(&snext[jx], cx);
    atomicAdd(&snext[jx + 1], cy);
}

// ---------------------------------------------------------------------------
// Kernel 5: loss = 0.001 * sum_ij a_i K_ij (1/s20_j) * (-0.1 ln K_ij)
// Same block/thread ownership as iter_k; one atomicAdd(out) per block.
// ---------------------------------------------------------------------------
__global__ __launch_bounds__(1024) void loss_k(const float* __restrict__ Km,
                                               const float* __restrict__ a_glob,
                                               const float* __restrict__ s20,
                                               float* __restrict__ out) {
    __shared__ float part[16];
    __shared__ float a_lds[16];
    int t = threadIdx.x;
    int lane = t & 63, wv = t >> 6;
    int bid = blockIdx.x;
    int r0 = bid * 16;

    if (t < 16) a_lds[t] = a_glob[r0 + t];
    __syncthreads();

    float2 sv = *reinterpret_cast<const float2*>(&s20[2 * t]);
    float bx = 1.0f / sv.x, by = 1.0f / sv.y;

    float acc = 0.f;
    #pragma unroll
    for (int i = 0; i < 16; ++i) {
        float2 k2 = *reinterpret_cast<const float2*>(&Km[(size_t)(r0 + i) * B + 2 * t]);
        float ai = a_lds[i];
        acc += ai * (k2.x * bx * __logf(k2.x) + k2.y * by * __logf(k2.y));
    }
    #pragma unroll
    for (int m = 32; m >= 1; m >>= 1) acc += __shfl_xor(acc, m, 64);
    if (lane == 0) part[wv] = acc;
    __syncthreads();
    if (t == 0) {
        float s = 0.f;
        #pragma unroll
        for (int w = 0; w < 16; ++w) s += part[w];
        atomicAdd(out, -0.1f * 0.001f * s);
    }
}

// ---------------------------------------------------------------------------
extern "C" void kernel_launch(void* const* d_in, const int* in_sizes, int n_in,
                              void* d_out, int out_size, void* d_ws, size_t ws_size,
                              hipStream_t stream) {
    const float* ys = (const float*)d_in[0];
    const float* yt = (const float*)d_in[1];
    float* out = (float*)d_out;

    char* wsb = (char*)d_ws;
    _Float16* ps = (_Float16*)wsb;                               // 4 MB
    _Float16* pt = (_Float16*)(wsb + (size_t)B * C * 2);         // 4 MB
    float* Km    = (float*)(wsb + (size_t)2 * B * C * 2);        // 16.8 MB
    float* svec  = Km + (size_t)B * B;                           // 21*B
    float* a_glob = svec + (size_t)21 * B;                       // B

    (void)hipMemsetAsync(svec + B, 0, (size_t)20 * B * sizeof(float), stream);
    (void)hipMemsetAsync(out, 0, sizeof(float), stream);

    init1_k<<<8, 256, 0, stream>>>(svec);
    softmax_k<<<2 * B, 256, 0, stream>>>(ys, yt, ps, pt);
    cdist_k<<<dim3(16, 16), 256, 0, stream>>>(ps, pt, Km);

    for (int t = 1; t <= 20; ++t)
        iter_k<<<128, 1024, 0, stream>>>(Km, svec + (size_t)(t - 1) * B,
                                         svec + (size_t)t * B, a_glob);

    loss_k<<<128, 1024, 0, stream>>>(Km, a_glob, svec + (size_t)20 * B, out);
}